// Round 2
// baseline (377.994 us; speedup 1.0000x reference)
//
#include <hip/hip_runtime.h>

using u16 = unsigned short;
typedef __bf16 bf16x8 __attribute__((ext_vector_type(8)));
typedef unsigned short u16x8 __attribute__((ext_vector_type(8)));
typedef float floatx4 __attribute__((ext_vector_type(4)));

__device__ __forceinline__ u16 f2bf(float f) {
  union { float f; unsigned u; } c; c.f = f;
  unsigned u = c.u;
  u += 0x7fffu + ((u >> 16) & 1u);   // round-to-nearest-even
  return (u16)(u >> 16);
}
__device__ __forceinline__ float bf2f(u16 h) {
  union { unsigned u; float f; } c; c.u = ((unsigned)h) << 16; return c.f;
}

__device__ __forceinline__ void st_out(float* p, float v) { *p = v; }
__device__ __forceinline__ void st_out(u16* p, float v) { *p = f2bf(v); }

__device__ __forceinline__ void load16(const u16* g, u16* l) {
  __builtin_amdgcn_global_load_lds(
      (const __attribute__((address_space(1))) void*)g,
      (__attribute__((address_space(3))) void*)l, 16, 0, 0);
}

#define TILE 128
#define BK 64

// ---------------------------------------------------------------------------
// Legacy 128x128 tile GEMM core (m97-structure) — still used by rect/tri/opv.
// LDS: row r's 8 16B-chunks XOR-permuted (slot = m ^ (r&7)) -> 0 bank conflicts.
// ---------------------------------------------------------------------------
template<typename OutT>
__device__ __forceinline__ void gemm_core(
    const u16* __restrict__ A, int lda, long sA,
    const u16* __restrict__ Bt, int ldb, long sB,
    OutT* __restrict__ C, int ldc, long sC,
    int kmax, int bx, int by, int bz, int tid)
{
  __shared__ u16 As[TILE * BK];
  __shared__ u16 Bs[TILE * BK];

  const u16* Ab = A + bz * sA + (long)by * TILE * lda;
  const u16* Bb = Bt + bz * sB + (long)bx * TILE * ldb;

  int lane = tid & 63;
  int wm = ((tid >> 7) & 1) * 64;
  int wn = ((tid >> 6) & 1) * 64;

  floatx4 acc[4][4] = {};
  int arow = wm + (lane & 15);
  int brow = wn + (lane & 15);
  int q = lane >> 4;

  for (int k0 = 0; k0 < kmax; k0 += BK) {
    __syncthreads();
#pragma unroll
    for (int h = 0; h < 4; h++) {
      int cc = tid + h * 256;
      int row = cc >> 3, gm = (cc & 7) ^ (row & 7);
      load16(Ab + (long)row * lda + k0 + gm * 8, &As[cc * 8]);
    }
#pragma unroll
    for (int h = 0; h < 4; h++) {
      int cc = tid + h * 256;
      int row = cc >> 3, gm = (cc & 7) ^ (row & 7);
      load16(Bb + (long)row * ldb + k0 + gm * 8, &Bs[cc * 8]);
    }
    __builtin_amdgcn_s_waitcnt(0);
    __syncthreads();

#pragma unroll
    for (int kp = 0; kp < 2; kp++) {
      bf16x8 a[4], b[4];
#pragma unroll
      for (int i = 0; i < 4; i++) {
        int r = arow + i * 16;
        a[i] = *(const bf16x8*)&As[(r * 8 + ((kp * 4 + q) ^ (r & 7))) * 8];
      }
#pragma unroll
      for (int j = 0; j < 4; j++) {
        int r = brow + j * 16;
        b[j] = *(const bf16x8*)&Bs[(r * 8 + ((kp * 4 + q) ^ (r & 7))) * 8];
      }
#pragma unroll
      for (int i = 0; i < 4; i++)
#pragma unroll
        for (int j = 0; j < 4; j++)
          acc[i][j] = __builtin_amdgcn_mfma_f32_16x16x32_bf16(a[i], b[j], acc[i][j], 0, 0, 0);
    }
  }

  // epilogue: C/D layout col=lane&15, row=(lane>>4)*4+reg  [m89-verified]
  OutT* Cb = C + bz * sC;
  int colbase = bx * TILE + wn + (lane & 15);
  int rowbase = by * TILE + wm + ((lane >> 4) << 2);
#pragma unroll
  for (int i = 0; i < 4; i++)
#pragma unroll
    for (int j = 0; j < 4; j++) {
      int col = colbase + j * 16;
#pragma unroll
      for (int r = 0; r < 4; r++)
        st_out(&Cb[(long)(rowbase + i * 16 + r) * ldc + col], acc[i][j][r]);
    }
}

// Small rectangular GEMM (used for NT), XCD-contiguous remap
template<typename OutT>
__global__ __launch_bounds__(256, 2)
void gemm_rect(const u16* __restrict__ A, int lda, long sA,
               const u16* __restrict__ Bt, int ldb, long sB,
               OutT* __restrict__ C, int ldc, long sC, int K,
               int l2gx, int nO8s)
{
  int L = blockIdx.x;
  int t = ((L & 7) << nO8s) | (L >> 3);
  int bx = t & ((1 << l2gx) - 1), by = t >> l2gx;
  gemm_core<OutT>(A, lda, sA, Bt, ldb, sB, C, ldc, sC, K, bx, by, blockIdx.y, threadIdx.x);
}

// Causal S = Y @ x^T -> bf16 scores (scale pre-folded into Wq). 136 tiles/batch,
// XCD-grouped (17 contiguous triangle slots per XCD).
__global__ __launch_bounds__(256, 2)
void gemm_tri(const u16* __restrict__ A, int lda, long sA,
              const u16* __restrict__ Bt, int ldb, long sB,
              u16* __restrict__ C, int ldc, long sC, int K)
{
  int tp = blockIdx.x;                       // 0..135
  int t = (tp & 7) * 17 + (tp >> 3);
  int r = (int)((sqrtf(8.f * t + 1.f) - 1.f) * 0.5f);
  while ((r + 1) * (r + 2) / 2 <= t) ++r;
  while (r * (r + 1) / 2 > t) --r;
  int c = t - r * (r + 1) / 2;
  gemm_core<u16>(A, lda, sA, Bt, ldb, sB, C, ldc, sC, K, c, r, blockIdx.y, threadIdx.x);
}

// O = P @ V via VT; causal K-trim. XCD j runs long row (15-j) FIRST, then row j
// (longest-first: short blocks fill the tail). P-strip reuse stays in one XCD.
__global__ __launch_bounds__(256, 2)
void gemm_opv(const u16* __restrict__ P, int lda, long sA,
              const u16* __restrict__ VT, int ldb, long sB,
              float* __restrict__ C, int ldc, long sC)
{
  int L = blockIdx.x;                        // 0..127
  int j = L & 7, s = L >> 3;
  int by = (s < 8) ? 15 - j : j;
  int bx = s & 7;
  gemm_core<float>(P, lda, sA, VT, ldb, sB, C, ldc, sC,
                   (by + 1) * TILE, bx, by, blockIdx.y, threadIdx.x);
}

// ---------------------------------------------------------------------------
// 256x256-tile, BK=64, 8-wave, 8-phase counted-vmcnt core (m201 template),
// NOW with the fine per-phase interleave (m196's lever):
// Each phase = { ds_reads for THIS phase's MFMA quadrant | stage half-tile(s) |
//                barrier | lgkmcnt(0) | setprio(1) 16 MFMA setprio(0) | barrier }
// Quadrant rotation (aL,bL)->(aL,bH)->(aH,bH)->(aH,bL): adjacent phases use
// DISJOINT acc registers, so the matrix pipe keeps draining cluster N while
// cluster N+1's ds_reads issue -> LDS pipe (2300cy/Ktile) hides under MFMA
// (2480cy/Ktile) instead of alternating with it.
// ds_read distribution 12/4/8/0 per K-tile; lgkmcnt(0) inside every read-phase
// guarantees reads COMPLETE before the end barrier -> next-phase DMA stages
// into that region are WAR-safe.
// Staging (2 K-tiles ahead, 1/0/2/1 half-tiles per phase):
//   P1: A1(t+1)->nbuf   P3: B0,B1(t+2)->buf   P4: A0(t+2)->buf
// Single counted vmcnt(6) at P4 (3 half-tiles in flight in steady state);
// issue-order check: every half lands >=1 phase before its first ds_read.
// ---------------------------------------------------------------------------
template<typename OutT>
__device__ __forceinline__ void gemm_core256(
    const u16* __restrict__ A, int lda, long sA,
    const u16* __restrict__ Bt, int ldb, long sB,
    OutT* __restrict__ C, int ldc, long sC,
    int kmax, int bx, int by, int bz, int tid, u16* lds)
{
  const u16* Ab = A + bz * sA + (long)by * 256 * lda;
  const u16* Bb = Bt + bz * sB + (long)bx * 256 * ldb;

  const int lane = tid & 63, wid = tid >> 6;
  const int wm = wid >> 2;            // 0..1  (wave row: 128 rows)
  const int wn = wid & 3;             // 0..3  (wave col: 64 cols)
  const int l15 = lane & 15, q = lane >> 4;

  // staging: thread covers chunks cc0, cc1 of each 128x64 half-tile
  const int cc0 = tid, cc1 = tid + 512;
  const int r0 = cc0 >> 3, g0 = (cc0 & 7) ^ (r0 & 7);
  const int r1 = cc1 >> 3, g1 = (cc1 & 7) ^ (r1 & 7);

  const int NK = kmax >> 6;

  floatx4 acc[8][4] = {};

  auto STAGE_A = [&](int k, int half, int buf) {
    const u16* g = Ab + (long)(half * 128) * lda + k * 64;
    load16(g + (long)r0 * lda + g0 * 8, lds + buf + half * 8192 + cc0 * 8);
    load16(g + (long)r1 * lda + g1 * 8, lds + buf + half * 8192 + cc1 * 8);
  };
  auto STAGE_B = [&](int k, int half, int buf) {
    const u16* g = Bb + (long)(half * 128) * ldb + k * 64;
    load16(g + (long)r0 * ldb + g0 * 8, lds + buf + 16384 + half * 8192 + cc0 * 8);
    load16(g + (long)r1 * ldb + g1 * 8, lds + buf + 16384 + half * 8192 + cc1 * 8);
  };

  // prologue: tile0 {B0,B1,A0,A1}->buf0 ; tile1 {B0,B1,A0}->buf1 (A1(1) staged
  // at P1(0)). vmcnt(6): 3 newest halves (B0,B1,A0 of tile1) may stay in
  // flight; tile0 fully landed.
  STAGE_B(0, 0, 0); STAGE_B(0, 1, 0);
  STAGE_A(0, 0, 0); STAGE_A(0, 1, 0);
  if (NK > 1) {
    STAGE_B(1, 0, 32768); STAGE_B(1, 1, 32768);
    STAGE_A(1, 0, 32768);
    asm volatile("s_waitcnt vmcnt(6)" ::: "memory");
  } else {
    asm volatile("s_waitcnt vmcnt(0)" ::: "memory");
  }
  __builtin_amdgcn_s_barrier();

  const int s0 = (q ^ (l15 & 7)) * 8;         // slot (u16 units) for kp=0
  const int s1 = ((q + 4) ^ (l15 & 7)) * 8;   // slot for kp=1

  bf16x8 aL[2][4], aH[2][4], bL[2][2], bH[2][2];

  for (int t = 0; t < NK; ++t) {
    const int buf = (t & 1) ? 32768 : 0;
    const int nbuf = 32768 - buf;
    const int abase = buf + wm * 8192 + l15 * 64;
    const int bbase = buf + 16384 + (wn >> 1) * 8192 + ((wn & 1) * 64 + l15) * 64;

    // ---- P1: read aL(8)+bL(4) | stage A1(t+1)->nbuf | MFMA Q1 acc[0-3][0-1]
#pragma unroll
    for (int i = 0; i < 4; ++i) {
      aL[0][i] = *(const bf16x8*)&lds[abase + i * 1024 + s0];
      aL[1][i] = *(const bf16x8*)&lds[abase + i * 1024 + s1];
    }
#pragma unroll
    for (int j = 0; j < 2; ++j) {
      bL[0][j] = *(const bf16x8*)&lds[bbase + j * 1024 + s0];
      bL[1][j] = *(const bf16x8*)&lds[bbase + j * 1024 + s1];
    }
    if (t + 1 < NK) STAGE_A(t + 1, 1, nbuf);
    asm volatile("s_waitcnt lgkmcnt(8)" ::: "memory");  // 12 reads issued: early drain
    __builtin_amdgcn_s_barrier();
    asm volatile("s_waitcnt lgkmcnt(0)" ::: "memory");
    __builtin_amdgcn_s_setprio(1);
#pragma unroll
    for (int kp = 0; kp < 2; ++kp)
#pragma unroll
      for (int i = 0; i < 4; ++i)
#pragma unroll
        for (int j = 0; j < 2; ++j)
          acc[i][j] = __builtin_amdgcn_mfma_f32_16x16x32_bf16(aL[kp][i], bL[kp][j], acc[i][j], 0, 0, 0);
    __builtin_amdgcn_s_setprio(0);
    asm volatile("" ::: "memory");
    __builtin_amdgcn_s_barrier();

    // ---- P2: read bH(4) | MFMA Q2 acc[0-3][2-3]
#pragma unroll
    for (int j = 0; j < 2; ++j) {
      bH[0][j] = *(const bf16x8*)&lds[bbase + (2 + j) * 1024 + s0];
      bH[1][j] = *(const bf16x8*)&lds[bbase + (2 + j) * 1024 + s1];
    }
    asm volatile("" ::: "memory");
    __builtin_amdgcn_s_barrier();
    asm volatile("s_waitcnt lgkmcnt(0)" ::: "memory");
    __builtin_amdgcn_s_setprio(1);
#pragma unroll
    for (int kp = 0; kp < 2; ++kp)
#pragma unroll
      for (int i = 0; i < 4; ++i)
#pragma unroll
        for (int j = 0; j < 2; ++j)
          acc[i][2 + j] = __builtin_amdgcn_mfma_f32_16x16x32_bf16(aL[kp][i], bH[kp][j], acc[i][2 + j], 0, 0, 0);
    __builtin_amdgcn_s_setprio(0);
    asm volatile("" ::: "memory");
    __builtin_amdgcn_s_barrier();

    // ---- P3: read aH(8) | stage B0,B1(t+2)->buf | MFMA Q3 acc[4-7][2-3]
#pragma unroll
    for (int i = 0; i < 4; ++i) {
      aH[0][i] = *(const bf16x8*)&lds[abase + 4096 + i * 1024 + s0];
      aH[1][i] = *(const bf16x8*)&lds[abase + 4096 + i * 1024 + s1];
    }
    if (t + 2 < NK) { STAGE_B(t + 2, 0, buf); STAGE_B(t + 2, 1, buf); }
    asm volatile("" ::: "memory");
    __builtin_amdgcn_s_barrier();
    asm volatile("s_waitcnt lgkmcnt(0)" ::: "memory");
    __builtin_amdgcn_s_setprio(1);
#pragma unroll
    for (int kp = 0; kp < 2; ++kp)
#pragma unroll
      for (int i = 0; i < 4; ++i)
#pragma unroll
        for (int j = 0; j < 2; ++j)
          acc[4 + i][2 + j] = __builtin_amdgcn_mfma_f32_16x16x32_bf16(aH[kp][i], bH[kp][j], acc[4 + i][2 + j], 0, 0, 0);
    __builtin_amdgcn_s_setprio(0);
    asm volatile("" ::: "memory");
    __builtin_amdgcn_s_barrier();

    // ---- P4: stage A0(t+2)->buf | counted vmcnt | MFMA Q4 acc[4-7][0-1]
    if (t + 2 < NK) {
      STAGE_A(t + 2, 0, buf);
      asm volatile("s_waitcnt vmcnt(6)" ::: "memory");
    } else {
      asm volatile("s_waitcnt vmcnt(0)" ::: "memory");
    }
    __builtin_amdgcn_s_barrier();
    __builtin_amdgcn_s_setprio(1);
#pragma unroll
    for (int kp = 0; kp < 2; ++kp)
#pragma unroll
      for (int i = 0; i < 4; ++i)
#pragma unroll
        for (int j = 0; j < 2; ++j)
          acc[4 + i][j] = __builtin_amdgcn_mfma_f32_16x16x32_bf16(aH[kp][i], bL[kp][j], acc[4 + i][j], 0, 0, 0);
    __builtin_amdgcn_s_setprio(0);
    asm volatile("" ::: "memory");
    __builtin_amdgcn_s_barrier();
  }

  // epilogue: C/D layout col=lane&15, row=(lane>>4)*4+reg  [m89-verified]
  OutT* Cb = C + bz * sC;
  const int colbase = bx * 256 + wn * 64 + l15;
  const int rowbase = by * 256 + wm * 128 + (q << 2);
#pragma unroll
  for (int i = 0; i < 8; ++i)
#pragma unroll
    for (int j = 0; j < 4; ++j) {
      const int col = colbase + j * 16;
#pragma unroll
      for (int r = 0; r < 4; ++r)
        st_out(&Cb[(long)(rowbase + i * 16 + r) * ldc + col], acc[i][j][r]);
    }
}

// Merged projections on the 256^2 8-phase core.
// t<256: Y = xb @ NT^T (64 by x 4 bx) ; t>=256: VT = WvT @ xb^T (4 by x 64 bx).
// 512 blocks = exactly 2 uniform rounds at 1 block/CU; XCD-contiguous remap.
__global__ __launch_bounds__(512, 2)
void gemm256_proj(const u16* __restrict__ xb, const u16* __restrict__ NT,
                  const u16* __restrict__ WvT, u16* __restrict__ Yb,
                  u16* __restrict__ VT)
{
  extern __shared__ u16 lds[];
  int L = blockIdx.x;                  // 0..511
  int t = ((L & 7) << 6) | (L >> 3);   // 64 contiguous tiles per XCD
  bool h = (t >= 256);
  int tt = h ? (t - 256) : t;
  int bx = h ? (tt & 63) : (tt & 3);
  int by = h ? (tt >> 6) : (tt >> 2);
  gemm_core256<u16>(h ? WvT : xb, 1024, 0L,
                    h ? xb : NT, 1024, 0L,
                    h ? VT : Yb, h ? 16384 : 1024, 0L,
                    1024, bx, by, 0, (int)threadIdx.x, lds);
}

// fp32 -> bf16 with scale, 4 elems/thread
__global__ __launch_bounds__(256)
void cvt_x(const float4* __restrict__ x, u16* __restrict__ o, int n4, float scale)
{
  int i = blockIdx.x * 256 + threadIdx.x;
  if (i >= n4) return;
  float4 v = x[i];
  ushort4 r;
  r.x = f2bf(v.x * scale); r.y = f2bf(v.y * scale);
  r.z = f2bf(v.z * scale); r.w = f2bf(v.w * scale);
  *(ushort4*)(o + (long)i * 4) = r;
}

// W (d_in x d_out) fp32 -> W^T (d_out x d_in) bf16, LDS tiled
__global__ __launch_bounds__(256)
void cvt_w(const float* __restrict__ W, u16* __restrict__ O)
{
  const int D = 1024;
  __shared__ float t[64][65];
  int tid = threadIdx.x;
  int c = tid & 63, r = tid >> 6;
  int e0 = blockIdx.x * 64, d0 = blockIdx.y * 64;
  for (int rr = r; rr < 64; rr += 4)
    t[rr][c] = W[(long)(d0 + rr) * D + e0 + c];
  __syncthreads();
  for (int rr = r; rr < 64; rr += 4)
    O[(long)(e0 + rr) * D + d0 + c] = f2bf(t[c][rr]);
}

// causal softmax over bf16 scores, in-place; one block per row, 8 elems/thread
// (scores are pre-scaled: 1/32 folded into Wq)
__global__ __launch_bounds__(256)
void softmax_bf16(u16* __restrict__ S)
{
  const int T = 2048;
  int row = blockIdx.x & (T - 1);
  u16* Prow = S + (long)blockIdx.x * T;    // (bi*T+row)*T
  int n = row + 1;
  int tid = threadIdx.x, lane = tid & 63, wid = tid >> 6;
  int i0 = tid * 8;

  u16x8 pv = *(const u16x8*)(Prow + i0);
  float v[8];
  float lmax = -3.0e38f;
#pragma unroll
  for (int j = 0; j < 8; j++) {
    v[j] = (i0 + j < n) ? bf2f(pv[j]) : -3.0e38f;
    lmax = fmaxf(lmax, v[j]);
  }
  __shared__ float red[8];
#pragma unroll
  for (int o = 32; o > 0; o >>= 1) lmax = fmaxf(lmax, __shfl_down(lmax, o, 64));
  if (lane == 0) red[wid] = lmax;
  __syncthreads();
  float m = fmaxf(fmaxf(red[0], red[1]), fmaxf(red[2], red[3]));

  float lsum = 0.f;
#pragma unroll
  for (int j = 0; j < 8; j++) {
    float e = (i0 + j < n) ? __expf(v[j] - m) : 0.f;
    v[j] = e;
    lsum += e;
  }
#pragma unroll
  for (int o = 32; o > 0; o >>= 1) lsum += __shfl_down(lsum, o, 64);
  if (lane == 0) red[4 + wid] = lsum;
  __syncthreads();
  float inv = 1.0f / (red[4] + red[5] + red[6] + red[7]);

  u16x8 w;
#pragma unroll
  for (int j = 0; j < 8; j++) w[j] = f2bf(v[j] * inv);
  *(u16x8*)(Prow + i0) = w;
}

extern "C" void kernel_launch(void* const* d_in, const int* in_sizes, int n_in,
                              void* d_out, int out_size, void* d_ws, size_t ws_size,
                              hipStream_t stream)
{
  const int B = 8, T = 2048, D = 1024;
  const float* x  = (const float*)d_in[0];
  const float* Wq = (const float*)d_in[1];
  const float* Wk = (const float*)d_in[2];
  const float* Wv = (const float*)d_in[3];
  float* out = (float*)d_out;
  char* ws = (char*)d_ws;

  // layout (MB): xb 0-32 | WvT 32-34 | NT 34-36 | Yb 36-68 (Wqb@36,Wkb@38 dead
  // after NT gemm) | VT 68-100 | S bf16 @100 (8 MB/batch)
  u16* xb  = (u16*)(ws);
  u16* WvT = (u16*)(ws + (32ul << 20));
  u16* NT  = (u16*)(ws + (34ul << 20));
  u16* Yb  = (u16*)(ws + (36ul << 20));
  u16* Wqb = Yb;                            // transient
  u16* Wkb = (u16*)(ws + (38ul << 20));     // transient
  u16* VT  = (u16*)(ws + (68ul << 20));
  u16* S   = (u16*)(ws + (100ul << 20));

  const size_t OFF_S = 100ul << 20;
  int NB = 8;
  while (NB > 1 && OFF_S + (size_t)NB * T * T * 2 > ws_size) NB >>= 1;

  // one-time: allow 128 KiB dynamic LDS for the 8-phase core
  static bool attr_done = false;
  if (!attr_done) {
    hipFuncSetAttribute(reinterpret_cast<const void*>(gemm256_proj),
                        hipFuncAttributeMaxDynamicSharedMemorySize, 131072);
    attr_done = true;
  }

  cvt_x<<<(B * T * D / 4 + 255) / 256, 256, 0, stream>>>((const float4*)x, xb, B * T * D / 4, 1.0f);
  cvt_x<<<(D * D / 4 + 255) / 256, 256, 0, stream>>>((const float4*)Wq, Wqb, D * D / 4, 0.03125f);
  cvt_x<<<(D * D / 4 + 255) / 256, 256, 0, stream>>>((const float4*)Wk, Wkb, D * D / 4, 1.0f);
  cvt_w<<<dim3(16, 16), 256, 0, stream>>>(Wv, WvT);

  // NT[d',d] = sum_e Wk[d',e] Wq'[d,e]   (scale folded into Wq')
  gemm_rect<u16><<<dim3(64, 1), 256, 0, stream>>>(
      Wkb, D, 0L, Wqb, D, 0L, NT, D, 0L, D, 3, 3);
  // Y = xb @ NT^T  and  VT = WvT @ xb^T  in one dispatch (256^2 8-phase core)
  gemm256_proj<<<dim3(512, 1), 512, 131072, stream>>>(xb, NT, WvT, Yb, VT);

  for (int b0 = 0; b0 < B; b0 += NB) {
    gemm_tri<<<dim3(136, NB), 256, 0, stream>>>(
        Yb + (long)b0 * T * D, D, (long)T * D,
        xb + (long)b0 * T * D, D, (long)T * D,
        S, T, (long)T * T, D);
    softmax_bf16<<<NB * T, 256, 0, stream>>>(S);
    gemm_opv<<<dim3(128, NB), 256, 0, stream>>>(
        S, T, (long)T * T,
        VT + (long)b0 * T, B * T, (long)T,
        out + (long)b0 * T * D, D, (long)T * D);
  }
}

// Round 3
// 367.524 us; speedup vs baseline: 1.0285x; 1.0285x over previous
//
#include <hip/hip_runtime.h>

using u16 = unsigned short;
typedef __bf16 bf16x8 __attribute__((ext_vector_type(8)));
typedef unsigned short u16x8 __attribute__((ext_vector_type(8)));
typedef float floatx4 __attribute__((ext_vector_type(4)));

__device__ __forceinline__ u16 f2bf(float f) {
  union { float f; unsigned u; } c; c.f = f;
  unsigned u = c.u;
  u += 0x7fffu + ((u >> 16) & 1u);   // round-to-nearest-even
  return (u16)(u >> 16);
}
__device__ __forceinline__ float bf2f(u16 h) {
  union { unsigned u; float f; } c; c.u = ((unsigned)h) << 16; return c.f;
}

__device__ __forceinline__ void st_out(float* p, float v) { *p = v; }
__device__ __forceinline__ void st_out(u16* p, float v) { *p = f2bf(v); }

__device__ __forceinline__ void load16(const u16* g, u16* l) {
  __builtin_amdgcn_global_load_lds(
      (const __attribute__((address_space(1))) void*)g,
      (__attribute__((address_space(3))) void*)l, 16, 0, 0);
}

#define TILE 128
#define BK 64

// ---------------------------------------------------------------------------
// Legacy 128x128 tile GEMM core (m97-structure) — used by rect/tri/opv.
// LDS: row r's 8 16B-chunks XOR-permuted (slot = m ^ (r&7)) -> 0 bank conflicts.
// ---------------------------------------------------------------------------
template<typename OutT>
__device__ __forceinline__ void gemm_core(
    const u16* __restrict__ A, int lda, long sA,
    const u16* __restrict__ Bt, int ldb, long sB,
    OutT* __restrict__ C, int ldc, long sC,
    int kmax, int bx, int by, int bz, int tid)
{
  __shared__ u16 As[TILE * BK];
  __shared__ u16 Bs[TILE * BK];

  const u16* Ab = A + bz * sA + (long)by * TILE * lda;
  const u16* Bb = Bt + bz * sB + (long)bx * TILE * ldb;

  int lane = tid & 63;
  int wm = ((tid >> 7) & 1) * 64;
  int wn = ((tid >> 6) & 1) * 64;

  floatx4 acc[4][4] = {};
  int arow = wm + (lane & 15);
  int brow = wn + (lane & 15);
  int q = lane >> 4;

  for (int k0 = 0; k0 < kmax; k0 += BK) {
    __syncthreads();
#pragma unroll
    for (int h = 0; h < 4; h++) {
      int cc = tid + h * 256;
      int row = cc >> 3, gm = (cc & 7) ^ (row & 7);
      load16(Ab + (long)row * lda + k0 + gm * 8, &As[cc * 8]);
    }
#pragma unroll
    for (int h = 0; h < 4; h++) {
      int cc = tid + h * 256;
      int row = cc >> 3, gm = (cc & 7) ^ (row & 7);
      load16(Bb + (long)row * ldb + k0 + gm * 8, &Bs[cc * 8]);
    }
    __builtin_amdgcn_s_waitcnt(0);
    __syncthreads();

#pragma unroll
    for (int kp = 0; kp < 2; kp++) {
      bf16x8 a[4], b[4];
#pragma unroll
      for (int i = 0; i < 4; i++) {
        int r = arow + i * 16;
        a[i] = *(const bf16x8*)&As[(r * 8 + ((kp * 4 + q) ^ (r & 7))) * 8];
      }
#pragma unroll
      for (int j = 0; j < 4; j++) {
        int r = brow + j * 16;
        b[j] = *(const bf16x8*)&Bs[(r * 8 + ((kp * 4 + q) ^ (r & 7))) * 8];
      }
#pragma unroll
      for (int i = 0; i < 4; i++)
#pragma unroll
        for (int j = 0; j < 4; j++)
          acc[i][j] = __builtin_amdgcn_mfma_f32_16x16x32_bf16(a[i], b[j], acc[i][j], 0, 0, 0);
    }
  }

  // epilogue: C/D layout col=lane&15, row=(lane>>4)*4+reg  [m89-verified]
  OutT* Cb = C + bz * sC;
  int colbase = bx * TILE + wn + (lane & 15);
  int rowbase = by * TILE + wm + ((lane >> 4) << 2);
#pragma unroll
  for (int i = 0; i < 4; i++)
#pragma unroll
    for (int j = 0; j < 4; j++) {
      int col = colbase + j * 16;
#pragma unroll
      for (int r = 0; r < 4; r++)
        st_out(&Cb[(long)(rowbase + i * 16 + r) * ldc + col], acc[i][j][r]);
    }
}

// Small rectangular GEMM (used for NT), XCD-contiguous remap
template<typename OutT>
__global__ __launch_bounds__(256, 2)
void gemm_rect(const u16* __restrict__ A, int lda, long sA,
               const u16* __restrict__ Bt, int ldb, long sB,
               OutT* __restrict__ C, int ldc, long sC, int K,
               int l2gx, int nO8s)
{
  int L = blockIdx.x;
  int t = ((L & 7) << nO8s) | (L >> 3);
  int bx = t & ((1 << l2gx) - 1), by = t >> l2gx;
  gemm_core<OutT>(A, lda, sA, Bt, ldb, sB, C, ldc, sC, K, bx, by, blockIdx.y, threadIdx.x);
}

// Causal S = Y @ x^T -> bf16 scores (scale pre-folded into Wq). 136 tiles/batch.
// NEW: 2x2 super-block triangle walk. XCD j gets 17 consecutive super-block-
// ordered slots -> per-XCD working set = ~2 A-strips + 2 B-strips (~1 MB,
// L2-resident) instead of 17 B-strips (4.35 MB, thrashes 4 MB L2).
__global__ __launch_bounds__(256, 2)
void gemm_tri(const u16* __restrict__ A, int lda, long sA,
              const u16* __restrict__ Bt, int ldb, long sB,
              u16* __restrict__ C, int ldc, long sC, int K)
{
  int tp = blockIdx.x;                       // 0..135
  int g = (tp & 7) * 17 + (tp >> 3);         // 17 contiguous slots per XCD
  // walk 2x2 super-blocks of the 16-row tile-triangle; diag SB=3 tiles, off=4
  int sr = 0, sc = 0, pre = 0;
  for (;;) {
    int sz = (sr == sc) ? 3 : 4;
    if (pre + sz > g) break;
    pre += sz; ++sc;
    if (sc > sr) { ++sr; sc = 0; }
  }
  int w = g - pre;
  int r, c;
  if (sr == sc) { r = 2 * sr + (w > 0); c = 2 * sc + (w == 2); }
  else          { r = 2 * sr + (w >> 1); c = 2 * sc + (w & 1); }
  gemm_core<u16>(A, lda, sA, Bt, ldb, sB, C, ldc, sC, K, c, r, blockIdx.y, threadIdx.x);
}

// O = P @ V via VT; causal K-trim. XCD j runs long row (15-j) FIRST, then row j
// (longest-first: short blocks fill the tail). P-strip reuse stays in one XCD.
__global__ __launch_bounds__(256, 2)
void gemm_opv(const u16* __restrict__ P, int lda, long sA,
              const u16* __restrict__ VT, int ldb, long sB,
              float* __restrict__ C, int ldc, long sC)
{
  int L = blockIdx.x;                        // 0..127
  int j = L & 7, s = L >> 3;
  int by = (s < 8) ? 15 - j : j;
  int bx = s & 7;
  gemm_core<float>(P, lda, sA, VT, ldb, sB, C, ldc, sC,
                   (by + 1) * TILE, bx, by, blockIdx.y, threadIdx.x);
}

// ---------------------------------------------------------------------------
// 256x256-tile, BK=64, 8-wave, 8-phase counted-vmcnt core (kept from R2;
// measured == 128^2 core's 870 TF — frozen pending a different lever).
// ---------------------------------------------------------------------------
template<typename OutT>
__device__ __forceinline__ void gemm_core256(
    const u16* __restrict__ A, int lda, long sA,
    const u16* __restrict__ Bt, int ldb, long sB,
    OutT* __restrict__ C, int ldc, long sC,
    int kmax, int bx, int by, int bz, int tid, u16* lds)
{
  const u16* Ab = A + bz * sA + (long)by * 256 * lda;
  const u16* Bb = Bt + bz * sB + (long)bx * 256 * ldb;

  const int lane = tid & 63, wid = tid >> 6;
  const int wm = wid >> 2;            // 0..1  (wave row: 128 rows)
  const int wn = wid & 3;             // 0..3  (wave col: 64 cols)
  const int l15 = lane & 15, q = lane >> 4;

  const int cc0 = tid, cc1 = tid + 512;
  const int r0 = cc0 >> 3, g0 = (cc0 & 7) ^ (r0 & 7);
  const int r1 = cc1 >> 3, g1 = (cc1 & 7) ^ (r1 & 7);

  const int NK = kmax >> 6;

  floatx4 acc[8][4] = {};

  auto STAGE_A = [&](int k, int half, int buf) {
    const u16* g = Ab + (long)(half * 128) * lda + k * 64;
    load16(g + (long)r0 * lda + g0 * 8, lds + buf + half * 8192 + cc0 * 8);
    load16(g + (long)r1 * lda + g1 * 8, lds + buf + half * 8192 + cc1 * 8);
  };
  auto STAGE_B = [&](int k, int half, int buf) {
    const u16* g = Bb + (long)(half * 128) * ldb + k * 64;
    load16(g + (long)r0 * ldb + g0 * 8, lds + buf + 16384 + half * 8192 + cc0 * 8);
    load16(g + (long)r1 * ldb + g1 * 8, lds + buf + 16384 + half * 8192 + cc1 * 8);
  };

  STAGE_B(0, 0, 0); STAGE_B(0, 1, 0);
  STAGE_A(0, 0, 0); STAGE_A(0, 1, 0);
  if (NK > 1) {
    STAGE_B(1, 0, 32768); STAGE_B(1, 1, 32768);
    STAGE_A(1, 0, 32768);
    asm volatile("s_waitcnt vmcnt(6)" ::: "memory");
  } else {
    asm volatile("s_waitcnt vmcnt(0)" ::: "memory");
  }
  __builtin_amdgcn_s_barrier();

  const int s0 = (q ^ (l15 & 7)) * 8;
  const int s1 = ((q + 4) ^ (l15 & 7)) * 8;

  bf16x8 aL[2][4], aH[2][4], bL[2][2], bH[2][2];

  for (int t = 0; t < NK; ++t) {
    const int buf = (t & 1) ? 32768 : 0;
    const int nbuf = 32768 - buf;
    const int abase = buf + wm * 8192 + l15 * 64;
    const int bbase = buf + 16384 + (wn >> 1) * 8192 + ((wn & 1) * 64 + l15) * 64;

    // ---- P1
#pragma unroll
    for (int i = 0; i < 4; ++i) {
      aL[0][i] = *(const bf16x8*)&lds[abase + i * 1024 + s0];
      aL[1][i] = *(const bf16x8*)&lds[abase + i * 1024 + s1];
    }
#pragma unroll
    for (int j = 0; j < 2; ++j) {
      bL[0][j] = *(const bf16x8*)&lds[bbase + j * 1024 + s0];
      bL[1][j] = *(const bf16x8*)&lds[bbase + j * 1024 + s1];
    }
    if (t + 1 < NK) STAGE_A(t + 1, 1, nbuf);
    asm volatile("s_waitcnt lgkmcnt(8)" ::: "memory");
    __builtin_amdgcn_s_barrier();
    asm volatile("s_waitcnt lgkmcnt(0)" ::: "memory");
    __builtin_amdgcn_s_setprio(1);
#pragma unroll
    for (int kp = 0; kp < 2; ++kp)
#pragma unroll
      for (int i = 0; i < 4; ++i)
#pragma unroll
        for (int j = 0; j < 2; ++j)
          acc[i][j] = __builtin_amdgcn_mfma_f32_16x16x32_bf16(aL[kp][i], bL[kp][j], acc[i][j], 0, 0, 0);
    __builtin_amdgcn_s_setprio(0);
    asm volatile("" ::: "memory");
    __builtin_amdgcn_s_barrier();

    // ---- P2
#pragma unroll
    for (int j = 0; j < 2; ++j) {
      bH[0][j] = *(const bf16x8*)&lds[bbase + (2 + j) * 1024 + s0];
      bH[1][j] = *(const bf16x8*)&lds[bbase + (2 + j) * 1024 + s1];
    }
    asm volatile("" ::: "memory");
    __builtin_amdgcn_s_barrier();
    asm volatile("s_waitcnt lgkmcnt(0)" ::: "memory");
    __builtin_amdgcn_s_setprio(1);
#pragma unroll
    for (int kp = 0; kp < 2; ++kp)
#pragma unroll
      for (int i = 0; i < 4; ++i)
#pragma unroll
        for (int j = 0; j < 2; ++j)
          acc[i][2 + j] = __builtin_amdgcn_mfma_f32_16x16x32_bf16(aL[kp][i], bH[kp][j], acc[i][2 + j], 0, 0, 0);
    __builtin_amdgcn_s_setprio(0);
    asm volatile("" ::: "memory");
    __builtin_amdgcn_s_barrier();

    // ---- P3
#pragma unroll
    for (int i = 0; i < 4; ++i) {
      aH[0][i] = *(const bf16x8*)&lds[abase + 4096 + i * 1024 + s0];
      aH[1][i] = *(const bf16x8*)&lds[abase + 4096 + i * 1024 + s1];
    }
    if (t + 2 < NK) { STAGE_B(t + 2, 0, buf); STAGE_B(t + 2, 1, buf); }
    asm volatile("" ::: "memory");
    __builtin_amdgcn_s_barrier();
    asm volatile("s_waitcnt lgkmcnt(0)" ::: "memory");
    __builtin_amdgcn_s_setprio(1);
#pragma unroll
    for (int kp = 0; kp < 2; ++kp)
#pragma unroll
      for (int i = 0; i < 4; ++i)
#pragma unroll
        for (int j = 0; j < 2; ++j)
          acc[4 + i][2 + j] = __builtin_amdgcn_mfma_f32_16x16x32_bf16(aH[kp][i], bH[kp][j], acc[4 + i][2 + j], 0, 0, 0);
    __builtin_amdgcn_s_setprio(0);
    asm volatile("" ::: "memory");
    __builtin_amdgcn_s_barrier();

    // ---- P4
    if (t + 2 < NK) {
      STAGE_A(t + 2, 0, buf);
      asm volatile("s_waitcnt vmcnt(6)" ::: "memory");
    } else {
      asm volatile("s_waitcnt vmcnt(0)" ::: "memory");
    }
    __builtin_amdgcn_s_barrier();
    __builtin_amdgcn_s_setprio(1);
#pragma unroll
    for (int kp = 0; kp < 2; ++kp)
#pragma unroll
      for (int i = 0; i < 4; ++i)
#pragma unroll
        for (int j = 0; j < 2; ++j)
          acc[4 + i][j] = __builtin_amdgcn_mfma_f32_16x16x32_bf16(aH[kp][i], bL[kp][j], acc[4 + i][j], 0, 0, 0);
    __builtin_amdgcn_s_setprio(0);
    asm volatile("" ::: "memory");
    __builtin_amdgcn_s_barrier();
  }

  OutT* Cb = C + bz * sC;
  const int colbase = bx * 256 + wn * 64 + l15;
  const int rowbase = by * 256 + wm * 128 + (q << 2);
#pragma unroll
  for (int i = 0; i < 8; ++i)
#pragma unroll
    for (int j = 0; j < 4; ++j) {
      const int col = colbase + j * 16;
#pragma unroll
      for (int r = 0; r < 4; ++r)
        st_out(&Cb[(long)(rowbase + i * 16 + r) * ldc + col], acc[i][j][r]);
    }
}

// Merged projections on the 256^2 8-phase core.
__global__ __launch_bounds__(512, 2)
void gemm256_proj(const u16* __restrict__ xb, const u16* __restrict__ NT,
                  const u16* __restrict__ WvT, u16* __restrict__ Yb,
                  u16* __restrict__ VT)
{
  extern __shared__ u16 lds[];
  int L = blockIdx.x;                  // 0..511
  int t = ((L & 7) << 6) | (L >> 3);   // 64 contiguous tiles per XCD
  bool h = (t >= 256);
  int tt = h ? (t - 256) : t;
  int bx = h ? (tt & 63) : (tt & 3);
  int by = h ? (tt >> 6) : (tt >> 2);
  gemm_core256<u16>(h ? WvT : xb, 1024, 0L,
                    h ? xb : NT, 1024, 0L,
                    h ? VT : Yb, h ? 16384 : 1024, 0L,
                    1024, bx, by, 0, (int)threadIdx.x, lds);
}

// fp32 -> bf16 with scale, 4 elems/thread
__global__ __launch_bounds__(256)
void cvt_x(const float4* __restrict__ x, u16* __restrict__ o, int n4, float scale)
{
  int i = blockIdx.x * 256 + threadIdx.x;
  if (i >= n4) return;
  float4 v = x[i];
  ushort4 r;
  r.x = f2bf(v.x * scale); r.y = f2bf(v.y * scale);
  r.z = f2bf(v.z * scale); r.w = f2bf(v.w * scale);
  *(ushort4*)(o + (long)i * 4) = r;
}

// Wq (scaled 1/32) and Wk converts merged into one dispatch
__global__ __launch_bounds__(256)
void cvt_qk(const float4* __restrict__ Wq, const float4* __restrict__ Wk,
            u16* __restrict__ oq, u16* __restrict__ ok, int n4)
{
  int i = blockIdx.x * 256 + threadIdx.x;
  if (i < n4) {
    float4 v = Wq[i];
    ushort4 r;
    r.x = f2bf(v.x * 0.03125f); r.y = f2bf(v.y * 0.03125f);
    r.z = f2bf(v.z * 0.03125f); r.w = f2bf(v.w * 0.03125f);
    *(ushort4*)(oq + (long)i * 4) = r;
  } else if (i < 2 * n4) {
    int k = i - n4;
    float4 v = Wk[k];
    ushort4 r;
    r.x = f2bf(v.x); r.y = f2bf(v.y); r.z = f2bf(v.z); r.w = f2bf(v.w);
    *(ushort4*)(ok + (long)k * 4) = r;
  }
}

// W (d_in x d_out) fp32 -> W^T (d_out x d_in) bf16, LDS tiled
__global__ __launch_bounds__(256)
void cvt_w(const float* __restrict__ W, u16* __restrict__ O)
{
  const int D = 1024;
  __shared__ float t[64][65];
  int tid = threadIdx.x;
  int c = tid & 63, r = tid >> 6;
  int e0 = blockIdx.x * 64, d0 = blockIdx.y * 64;
  for (int rr = r; rr < 64; rr += 4)
    t[rr][c] = W[(long)(d0 + rr) * D + e0 + c];
  __syncthreads();
  for (int rr = r; rr < 64; rr += 4)
    O[(long)(e0 + rr) * D + d0 + c] = f2bf(t[c][rr]);
}

// causal softmax over bf16 scores, in-place; one block per row, 8 elems/thread.
// NEW: causal trim — opv block for strip by reads cols [0, (by+1)*128) only,
// and round_up(n,128) == (by+1)*128 for EVERY row of the strip. So threads
// with i0 >= W skip load+store entirely (still join barriers/shuffles);
// [n, W) is written as zeros (opv reads it). Halves S traffic and expf work.
__global__ __launch_bounds__(256)
void softmax_bf16(u16* __restrict__ S)
{
  const int T = 2048;
  int row = blockIdx.x & (T - 1);
  u16* Prow = S + (long)blockIdx.x * T;    // (bi*T+row)*T
  int n = row + 1;
  int W = ((row >> 7) + 1) << 7;           // cols opv will read
  int tid = threadIdx.x, lane = tid & 63, wid = tid >> 6;
  int i0 = tid * 8;
  bool act = (i0 < W);

  float v[8];
  float lmax = -3.0e38f;
  if (act) {
    u16x8 pv = *(const u16x8*)(Prow + i0);
#pragma unroll
    for (int j = 0; j < 8; j++) {
      v[j] = (i0 + j < n) ? bf2f(pv[j]) : -3.0e38f;
      lmax = fmaxf(lmax, v[j]);
    }
  }
  __shared__ float red[8];
#pragma unroll
  for (int o = 32; o > 0; o >>= 1) lmax = fmaxf(lmax, __shfl_down(lmax, o, 64));
  if (lane == 0) red[wid] = lmax;
  __syncthreads();
  float m = fmaxf(fmaxf(red[0], red[1]), fmaxf(red[2], red[3]));

  float lsum = 0.f;
  if (act) {
#pragma unroll
    for (int j = 0; j < 8; j++) {
      float e = (i0 + j < n) ? __expf(v[j] - m) : 0.f;
      v[j] = e;
      lsum += e;
    }
  }
#pragma unroll
  for (int o = 32; o > 0; o >>= 1) lsum += __shfl_down(lsum, o, 64);
  if (lane == 0) red[4 + wid] = lsum;
  __syncthreads();
  float inv = 1.0f / (red[4] + red[5] + red[6] + red[7]);

  if (act) {
    u16x8 w;
#pragma unroll
    for (int j = 0; j < 8; j++) w[j] = f2bf(v[j] * inv);
    *(u16x8*)(Prow + i0) = w;
  }
}

extern "C" void kernel_launch(void* const* d_in, const int* in_sizes, int n_in,
                              void* d_out, int out_size, void* d_ws, size_t ws_size,
                              hipStream_t stream)
{
  const int B = 8, T = 2048, D = 1024;
  const float* x  = (const float*)d_in[0];
  const float* Wq = (const float*)d_in[1];
  const float* Wk = (const float*)d_in[2];
  const float* Wv = (const float*)d_in[3];
  float* out = (float*)d_out;
  char* ws = (char*)d_ws;

  // layout (MB): xb 0-32 | WvT 32-34 | NT 34-36 | Yb 36-68 (Wqb@36,Wkb@38 dead
  // after NT gemm) | VT 68-100 | S bf16 @100 (8 MB/batch)
  u16* xb  = (u16*)(ws);
  u16* WvT = (u16*)(ws + (32ul << 20));
  u16* NT  = (u16*)(ws + (34ul << 20));
  u16* Yb  = (u16*)(ws + (36ul << 20));
  u16* Wqb = Yb;                            // transient
  u16* Wkb = (u16*)(ws + (38ul << 20));     // transient
  u16* VT  = (u16*)(ws + (68ul << 20));
  u16* S   = (u16*)(ws + (100ul << 20));

  const size_t OFF_S = 100ul << 20;
  int NB = 8;
  while (NB > 1 && OFF_S + (size_t)NB * T * T * 2 > ws_size) NB >>= 1;

  // one-time: allow 128 KiB dynamic LDS for the 8-phase core
  static bool attr_done = false;
  if (!attr_done) {
    hipFuncSetAttribute(reinterpret_cast<const void*>(gemm256_proj),
                        hipFuncAttributeMaxDynamicSharedMemorySize, 131072);
    attr_done = true;
  }

  cvt_x<<<(B * T * D / 4 + 255) / 256, 256, 0, stream>>>((const float4*)x, xb, B * T * D / 4, 1.0f);
  cvt_qk<<<(2 * D * D / 4 + 255) / 256, 256, 0, stream>>>(
      (const float4*)Wq, (const float4*)Wk, Wqb, Wkb, D * D / 4);
  cvt_w<<<dim3(16, 16), 256, 0, stream>>>(Wv, WvT);

  // NT[d',d] = sum_e Wk[d',e] Wq'[d,e]   (scale folded into Wq')
  gemm_rect<u16><<<dim3(64, 1), 256, 0, stream>>>(
      Wkb, D, 0L, Wqb, D, 0L, NT, D, 0L, D, 3, 3);
  // Y = xb @ NT^T  and  VT = WvT @ xb^T  in one dispatch (256^2 8-phase core)
  gemm256_proj<<<dim3(512, 1), 512, 131072, stream>>>(xb, NT, WvT, Yb, VT);

  for (int b0 = 0; b0 < B; b0 += NB) {
    gemm_tri<<<dim3(136, NB), 256, 0, stream>>>(
        Yb + (long)b0 * T * D, D, (long)T * D,
        xb + (long)b0 * T * D, D, (long)T * D,
        S, T, (long)T * T, D);
    softmax_bf16<<<NB * T, 256, 0, stream>>>(S);
    gemm_opv<<<dim3(128, NB), 256, 0, stream>>>(
        S, T, (long)T * T,
        VT + (long)b0 * T, B * T, (long)T,
        out + (long)b0 * T * D, D, (long)T * D);
  }
}